// Round 7
// baseline (56.320 us; speedup 1.0000x reference)
//
#include <hip/hip_runtime.h>

#define HID 64
#define VOC 64
#define NSLOT 8
#define NB 256
#define SEQL 2048
#define NT 512            // 8 waves; wave w computes vocab rows w*8..w*8+7
#define HPAD 65           // hlds pitch: conflict-free
#define MAGIC2 0x5EEDF00D

// ---------------------------------------------------------------------------
// Single kernel, 256 blocks x 512 threads, zero auxiliary nodes.
// Each block redundantly computes the 64-row vocab table with the PROVEN
// shfl-broadcast FFN scheme (per-lane coalesced weight reads from LDS-staged
// w1/w2; NO wave-uniform loads -> no s_load/lgkmcnt serialization, the r5/r6
// bottleneck). 8 rows per wave batched so each weight value is loaded once
// and reused for 8 FMAs. Then: histogram (overlapped) -> rank -> greedy
// top-8 multiset -> attention -> entropy gate -> logits.
// Entropy mean: each block publishes ent via relaxed agent atomic store +
// release flag (r6-proven pattern); block 255 polls all 256 flags, does a
// deterministic tree reduce, writes the mean, resets flags to 0 (poison
// 0xAAAAAAAA != MAGIC2 => poison-safe; reset => replay-safe).
// ---------------------------------------------------------------------------
__global__ __launch_bounds__(NT) void fused_kernel(
    const int* __restrict__ seq,
    const float* __restrict__ embed, const float* __restrict__ w1, const float* __restrict__ b1,
    const float* __restrict__ w2, const float* __restrict__ b2,
    const float* __restrict__ ln_g, const float* __restrict__ ln_b,
    const float* __restrict__ gate_w, const float* __restrict__ gate_b,
    const float* __restrict__ q_w, const float* __restrict__ q_b,
    const float* __restrict__ out_w, const float* __restrict__ out_b,
    float* __restrict__ out, float* __restrict__ entw, int* __restrict__ dflags)
{
    __shared__ float sw1[2 * HID * HID];   // 32 KB, [i][j] at i*128+j
    __shared__ float sw2[2 * HID * HID];   // 32 KB, [j][i] at j*64+i
    __shared__ float hlds[VOC * HPAD];     // 16.6 KB, h rows
    __shared__ float sscore[VOC];
    __shared__ int   sorder[VOC];
    __shared__ int   hist[VOC];
    __shared__ float sqv[HID];
    __shared__ float sctx[HID];
    __shared__ int   svids[NSLOT];
    __shared__ float sla[NSLOT];
    __shared__ float seff[NSLOT];
    __shared__ float sred[NB];
    __shared__ int   shvlast;

    const int t = threadIdx.x;
    const int b = blockIdx.x;
    const int lane = t & 63;
    const int wave = t >> 6;

    // Own seq row (2048 ints = 512 int4, one per thread).
    const int4 a = ((const int4*)(seq + (size_t)b * SEQL))[t];

    // Stage w1/w2 into LDS (float4, coalesced; once per block, reused 8x).
    for (int p = t; p < 2 * HID * HID / 4; p += NT)
        ((float4*)sw1)[p] = ((const float4*)w1)[p];
    for (int p = t; p < 2 * HID * HID / 4; p += NT)
        ((float4*)sw2)[p] = ((const float4*)w2)[p];
    if (t < VOC) hist[t] = 0;
    if (t == NT - 1) shvlast = a.w;        // seq[b][2047]
    __syncthreads();

    // Histogram (LDS atomics, fire-and-forget).
    atomicAdd(&hist[a.x], 1);
    atomicAdd(&hist[a.y], 1);
    atomicAdd(&hist[a.z], 1);
    atomicAdd(&hist[a.w], 1);

    // ---- FFN + LN + score for rows r0..r0+7 (r0 = wave*8) -----------------
    {
        const int r0 = wave * 8;
        const float b1a = b1[lane], b1b = b1[HID + lane];
        const float b2v = b2[lane];
        const float lng = ln_g[lane], lnb = ln_b[lane], gwv = gate_w[lane];
        const float gbv = gate_b[0];

        float e[8];
#pragma unroll
        for (int r = 0; r < 8; ++r) e[r] = embed[(r0 + r) * HID + lane];

        // FFN1: lane = hidden unit j (and j+64); 8 rows share each weight.
        float fa[8], fb[8];
#pragma unroll
        for (int r = 0; r < 8; ++r) { fa[r] = b1a; fb[r] = b1b; }
#pragma unroll 4
        for (int i = 0; i < HID; ++i) {
            const float wa = sw1[i * 2 * HID + lane];
            const float wb = sw1[i * 2 * HID + HID + lane];
#pragma unroll
            for (int r = 0; r < 8; ++r) {
                const float ev = __shfl(e[r], i);
                fa[r] = fmaf(ev, wa, fa[r]);
                fb[r] = fmaf(ev, wb, fb[r]);
            }
        }
#pragma unroll
        for (int r = 0; r < 8; ++r) {
            fa[r] = fmaxf(fa[r], 0.0f);
            fb[r] = fmaxf(fb[r], 0.0f);
        }

        // FFN2 + residual: lane = output unit i.
        float z[8];
#pragma unroll
        for (int r = 0; r < 8; ++r) z[r] = e[r] + b2v;
#pragma unroll 4
        for (int j = 0; j < HID; ++j) {
            const float wv = sw2[j * HID + lane];
#pragma unroll
            for (int r = 0; r < 8; ++r)
                z[r] = fmaf(__shfl(fa[r], j), wv, z[r]);
        }
#pragma unroll 4
        for (int j = 0; j < HID; ++j) {
            const float wv = sw2[(HID + j) * HID + lane];
#pragma unroll
            for (int r = 0; r < 8; ++r)
                z[r] = fmaf(__shfl(fb[r], j), wv, z[r]);
        }

        // LayerNorm + gate score per row (wave butterflies).
#pragma unroll
        for (int r = 0; r < 8; ++r) {
            float s = z[r];
#pragma unroll
            for (int m = 32; m; m >>= 1) s += __shfl_xor(s, m);
            const float mu = s * (1.0f / HID);
            const float d = z[r] - mu;
            float vs = d * d;
#pragma unroll
            for (int m = 32; m; m >>= 1) vs += __shfl_xor(vs, m);
            const float inv = 1.0f / sqrtf(vs * (1.0f / HID) + 1e-5f);
            const float h = d * inv * lng + lnb;
            hlds[(r0 + r) * HPAD + lane] = h;
            float sc = h * gwv;
#pragma unroll
            for (int m = 32; m; m >>= 1) sc += __shfl_xor(sc, m);
            if (lane == 0) sscore[r0 + r] = sc + gbv;
        }
    }
    __syncthreads();

    // ---- rank ids (t<64) ; q row of last token (t in [64,128)) ------------
    if (t < VOC) {
        const float sv = sscore[t];
        int r = 0;
        for (int u = 0; u < VOC; ++u) {
            const float su = sscore[u];
            if (su > sv || (su == sv && u < t)) ++r;
        }
        sorder[r] = t;
    } else if (t < 2 * VOC) {
        const int i = t - VOC;
        const int vlast = shvlast;
        float qa = q_b[i];
        for (int k = 0; k < HID; ++k)
            qa = fmaf(hlds[vlast * HPAD + k], q_w[k * HID + i], qa);
        sqv[i] = qa;
    }
    __syncthreads();

    // ---- greedy top-8 multiset by descending score with multiplicity ------
    if (t == 0) {
        int r = NSLOT, n = 0, pos = 0;
        while (r > 0) {
            const int v = sorder[pos++];
            int c = hist[v];
            if (c > r) c = r;
            for (int k = 0; k < c; ++k) svids[n++] = v;
            r -= c;
        }
    }
    __syncthreads();

    // ---- attention logits: 8 lanes per slot, 3-step shfl reduce -----------
    if (t < VOC) {
        const int k = t >> 3, e2 = t & 7;
        const float* hr = &hlds[svids[k] * HPAD];
        float p = 0.0f;
#pragma unroll
        for (int m = 0; m < 8; ++m)
            p = fmaf(hr[e2 + 8 * m], sqv[e2 + 8 * m], p);
        p += __shfl_xor(p, 1);
        p += __shfl_xor(p, 2);
        p += __shfl_xor(p, 4);
        if (e2 == 0) sla[k] = p * 0.125f;  // 1/sqrt(64)
    }
    __syncthreads();

    // ---- softmax + entropy gate; publish entropy (r6-proven handshake) ----
    if (t == 0) {
        float m = -1e30f;
        for (int k = 0; k < NSLOT; ++k) m = fmaxf(m, sla[k]);
        float e2[NSLOT], s = 0.0f;
        for (int k = 0; k < NSLOT; ++k) { e2[k] = expf(sla[k] - m); s += e2[k]; }
        const float invs = 1.0f / s;
        float ent = 0.0f;
        for (int k = 0; k < NSLOT; ++k) {
            const float av = e2[k] * invs;
            ent -= av * logf(av + 1e-9f);
        }
        const float high = (ent > 1.5f) ? 1.0f : 0.0f;
        for (int k = 0; k < NSLOT; ++k)
            seff[k] = (1.0f - high) * (e2[k] * invs) + high * (1.0f / NSLOT);
        __hip_atomic_store(&entw[b], ent, __ATOMIC_RELAXED,
                           __HIP_MEMORY_SCOPE_AGENT);
        __hip_atomic_store(&dflags[b], MAGIC2, __ATOMIC_RELEASE,
                           __HIP_MEMORY_SCOPE_AGENT);
    }
    __syncthreads();

    // ---- ctx then logits --------------------------------------------------
    if (t < HID) {
        float cx = 0.0f;
#pragma unroll
        for (int k = 0; k < NSLOT; ++k)
            cx = fmaf(seff[k], hlds[svids[k] * HPAD + t], cx);
        sctx[t] = cx;
    }
    __syncthreads();
    if (t < VOC) {
        float o = out_b[t];
        for (int i = 0; i < HID; ++i)
            o = fmaf(sctx[i], out_w[i * VOC + t], o);
        out[(size_t)b * VOC + t] = o;
    }

    // ---- block 255: gather entropies, deterministic reduce, reset flags ---
    if (b == NB - 1) {
        __syncthreads();
        if (t < NB) {
            while (__hip_atomic_load(&dflags[t], __ATOMIC_ACQUIRE,
                                     __HIP_MEMORY_SCOPE_AGENT) != MAGIC2)
                __builtin_amdgcn_s_sleep(8);
            const float v = __hip_atomic_load(&entw[t], __ATOMIC_RELAXED,
                                              __HIP_MEMORY_SCOPE_AGENT);
            __hip_atomic_store(&dflags[t], 0, __ATOMIC_RELAXED,
                               __HIP_MEMORY_SCOPE_AGENT);
            sred[t] = v;
        }
        __syncthreads();
        for (int s = NB / 2; s > 0; s >>= 1) {
            if (t < s) sred[t] += sred[t + s];
            __syncthreads();
        }
        if (t == 0) out[(size_t)NB * VOC] = sred[0] * (1.0f / NB);
    }
}

extern "C" void kernel_launch(void* const* d_in, const int* in_sizes, int n_in,
                              void* d_out, int out_size, void* d_ws, size_t ws_size,
                              hipStream_t stream) {
    const int*   seq    = (const int*)  d_in[0];
    const float* embed  = (const float*)d_in[1];
    const float* w1     = (const float*)d_in[2];
    const float* b1     = (const float*)d_in[3];
    const float* w2     = (const float*)d_in[4];
    const float* b2     = (const float*)d_in[5];
    const float* ln_g   = (const float*)d_in[6];
    const float* ln_b   = (const float*)d_in[7];
    const float* gate_w = (const float*)d_in[8];
    const float* gate_b = (const float*)d_in[9];
    const float* q_w    = (const float*)d_in[10];
    const float* q_b    = (const float*)d_in[11];
    const float* out_w  = (const float*)d_in[12];
    const float* out_b  = (const float*)d_in[13];
    float* out = (float*)d_out;

    float* entw   = (float*)d_ws;           // 256 floats
    int*   dflags = (int*)d_ws + NB;        // 256 ints

    fused_kernel<<<NB, NT, 0, stream>>>(seq, embed, w1, b1, w2, b2,
                                        ln_g, ln_b, gate_w, gate_b,
                                        q_w, q_b, out_w, out_b,
                                        out, entw, dflags);
}